// Round 6
// baseline (610.622 us; speedup 1.0000x reference)
//
#include <hip/hip_runtime.h>
#include <hip/hip_cooperative_groups.h>
#include <math.h>

namespace cg = cooperative_groups;

#define NI 100000
#define NO 50000
#define NE 100000
#define NB (NI + NO)          // 150000 combined dst bins
#define TOTE (2 * NE)         // 200000

// ---- ws layout (4B units) ----
#define OFF_WRT_OI    0         // 1024
#define OFF_WRT_IO    1024      // 1024
#define OFF_WFRAG     2048      // 9216 dwords = 2304 uint4
#define OFF_Y2Z2      11264     // 600000
#define OFF_SCANNED   611264    // 150016 ints
#define OFF_BLOCKSUM  761280    // 640 ints
#define OFF_BLOCKPREF 761920    // 640 ints
#define OFF_SORTED    762560    // 200000 ints
#define OFF_DSTS      962560    // 200000 ints
#define OFF_RANK      1162560   // 200000 ints
#define OFF_ACC       1362560   // 4800000 floats
#define OFF_CNT       6162560   // 150016 ints
// total ~25.3 MB

static constexpr int B_EDGE = (NE + 255) / 256;        // 391
static constexpr int SCAN_BLOCKS = (NB + 255) / 256;   // 586

typedef __attribute__((ext_vector_type(8))) short short8;
typedef __attribute__((ext_vector_type(4))) float f32x4;

struct Params {
    const float *x_ind, *x_org;
    const int *src_oi, *dst_oi; const float* attr_oi;
    const int *src_io, *dst_io; const float* attr_io;
    const float *Wm_oi, *bm_oi, *Wr_oi, *b_oi;
    const float *Wm_io, *bm_io, *Wr_io, *b_io;
    const float *Wm2, *bm2, *Wr2, *b2;
    float* ws; float* out;
};

__device__ __forceinline__ float sigmoidf_fast(float x) {
    return 1.0f / (1.0f + __expf(-x));
}
__device__ __forceinline__ unsigned f2bf(float f) {   // RTNE to bf16
    unsigned u = __float_as_uint(f);
    return (u + 0x7FFFu + ((u >> 16) & 1u)) >> 16;
}
__device__ __forceinline__ unsigned pack_trunc(float lo, float hi) {
    return __builtin_amdgcn_perm(__float_as_uint(hi), __float_as_uint(lo), 0x07060302u);
}

// ---------------------------------------------------------------- the one kernel
__global__ __launch_bounds__(256, 2) void k_mega(Params p)
{
    __shared__ uint4 xstage[4][256];      // 16 KB (edge phase)
    __shared__ float stage[256 * 36];     // 36 KB (edge phase; scan scratch aliases)

    cg::grid_group grid = cg::this_grid();
    const int tid = threadIdx.x;
    const int gsz = (int)gridDim.x;
    const int gid = (int)blockIdx.x * 256 + tid;
    const int gstride = gsz * 256;

    float* ws = p.ws;
    int* cnt       = (int*)(ws + OFF_CNT);
    int* scanned   = (int*)(ws + OFF_SCANNED);
    int* blocksum  = (int*)(ws + OFF_BLOCKSUM);
    int* blockpref = (int*)(ws + OFF_BLOCKPREF);
    int* sorted    = (int*)(ws + OFF_SORTED);
    int* dsts      = (int*)(ws + OFF_DSTS);
    int* rank      = (int*)(ws + OFF_RANK);
    float* acc     = ws + OFF_ACC;
    float* y2z2    = ws + OFF_Y2Z2;

    // ================= P0: zero acc + cnt, WrT transposes, MFMA B-frag prep
    {
        float4* a4 = (float4*)acc;
        float4 z4 = make_float4(0.f, 0.f, 0.f, 0.f);
        for (int q = gid; q < 1200000; q += gstride) a4[q] = z4;
        for (int q = gid; q < 150016; q += gstride) cnt[q] = 0;
        if (gid < 1024)       ws[OFF_WRT_OI + gid] = p.Wr_oi[(gid & 31) * 32 + (gid >> 5)];
        else if (gid < 2048)  { int v = gid - 1024; ws[OFF_WRT_IO + v] = p.Wr_io[(v & 31) * 32 + (v >> 5)]; }
        int u = gid - 2048;
        if (u >= 0 && u < 2304) {
            int rel = u >= 1152;                 // 0 = oi, 1 = io
            int v = u - rel * 1152;
            int lane = v & 63;
            int fi = v >> 6;                     // 0..17
            int a = fi >> 1;                     // 0..8
            int nt = fi & 1;
            int quad = lane >> 4;
            int n = nt * 16 + (lane & 15);
            const float* Wm = rel ? p.Wm_io : p.Wm_oi;
            const float* bm = rel ? p.bm_io : p.bm_oi;
            unsigned pk[4];
            #pragma unroll
            for (int d = 0; d < 4; d++) {
                int k0 = quad * 8 + 2 * d;
                float vlo = (a < 8) ? Wm[a * 1024 + k0 * 32 + n]       : bm[k0 * 32 + n];
                float vhi = (a < 8) ? Wm[a * 1024 + (k0 + 1) * 32 + n] : bm[(k0 + 1) * 32 + n];
                pk[d] = f2bf(vlo) | (f2bf(vhi) << 16);
            }
            uint4* wf = (uint4*)(ws + OFF_WFRAG);
            wf[((rel * 9 + a) * 2 + nt) * 64 + lane] = make_uint4(pk[0], pk[1], pk[2], pk[3]);
        }
    }
    __threadfence();
    grid.sync();

    // ================= P1: dst histogram + within-dst rank
    for (int idx = gid; idx < TOTE; idx += gstride) {
        bool is_io = idx >= NE;
        int e = is_io ? idx - NE : idx;
        int cd = is_io ? (NI + p.dst_io[e]) : p.dst_oi[e];
        rank[idx] = atomicAdd(&cnt[cd], 1);
    }
    __threadfence();
    grid.sync();

    // ================= P2a: per-256-chunk exclusive scan
    {
        int* wsum = (int*)stage;              // 4 ints scratch
        int lane = tid & 63, wv = tid >> 6;
        for (int bv = blockIdx.x; bv < SCAN_BLOCKS; bv += gsz) {
            int d = bv * 256 + tid;
            int v = (d < NB) ? cnt[d] : 0;
            int s = v;
            #pragma unroll
            for (int off = 1; off < 64; off <<= 1) {
                int t = __shfl_up(s, off);
                if (lane >= off) s += t;
            }
            if (lane == 63) wsum[wv] = s;
            __syncthreads();
            int add = 0;
            for (int w = 0; w < wv; w++) add += wsum[w];
            scanned[d] = s + add - v;
            if (tid == 255) blocksum[bv] = s + add;
            __syncthreads();                  // wsum reuse across bv iterations
        }
    }
    __threadfence();
    grid.sync();

    // ================= P2b: top-level scan of 586 block sums (block 0)
    if (blockIdx.x == 0) {
        int* L = (int*)stage;                 // 768 ints
        int* wsum2 = L + 768;                 // 4 ints
        int lane = tid & 63, wv = tid >> 6;
        #pragma unroll
        for (int j = 0; j < 3; j++) {
            int i = tid * 3 + j;
            L[tid * 3 + j] = (i < SCAN_BLOCKS) ? blocksum[i] : 0;
        }
        __syncthreads();
        int s0 = L[tid * 3], s1 = s0 + L[tid * 3 + 1], s2 = s1 + L[tid * 3 + 2];
        int sc = s2;
        #pragma unroll
        for (int off = 1; off < 64; off <<= 1) {
            int u = __shfl_up(sc, off);
            if (lane >= off) sc += u;
        }
        if (lane == 63) wsum2[wv] = sc;
        __syncthreads();
        int add2 = 0;
        for (int w = 0; w < wv; w++) add2 += wsum2[w];
        int excl = sc + add2 - s2;
        if (tid * 3     < SCAN_BLOCKS) blockpref[tid * 3]     = excl;
        if (tid * 3 + 1 < SCAN_BLOCKS) blockpref[tid * 3 + 1] = excl + s0;
        if (tid * 3 + 2 < SCAN_BLOCKS) blockpref[tid * 3 + 2] = excl + s1;
    }
    __threadfence();
    grid.sync();

    // ================= P3: scatter into sorted order (atomic-free via rank)
    for (int idx = gid; idx < TOTE; idx += gstride) {
        bool is_io = idx >= NE;
        int e = is_io ? idx - NE : idx;
        int cd = is_io ? (NI + p.dst_io[e]) : p.dst_oi[e];
        int pos = scanned[cd] + blockpref[cd >> 8] + rank[idx];
        sorted[pos] = e;
        dsts[pos] = cd;
    }
    __threadfence();
    grid.sync();

    // ================= P4: layer-1 edge messages via MFMA + segment reduce
    {
        int wave = tid >> 6, lane = tid & 63, quad = lane >> 4;
        for (int bv = blockIdx.x; bv < 2 * B_EDGE; bv += gsz) {
            bool is_io = bv >= B_EDGE;
            int blockStart = is_io ? (NE + (bv - B_EDGE) * 256) : (bv * 256);
            int relEnd = is_io ? TOTE : NE;
            int pp = blockStart + tid;
            bool act = pp < relEnd;

            const int*   srcA  = is_io ? p.src_io : p.src_oi;
            const float* attrA = is_io ? p.attr_io : p.attr_oi;
            const float* xsrc  = is_io ? p.x_ind : p.x_org;

            const uint4* wfr = ((const uint4*)(ws + OFF_WFRAG)) + (is_io ? 1152 : 0);
            uint4 bf[9][2];
            #pragma unroll
            for (int a = 0; a < 9; a++) {
                #pragma unroll
                for (int nt = 0; nt < 2; nt++)
                    bf[a][nt] = wfr[((a * 2 + nt) * 64) + lane];
            }

            int cd = -1;
            float ar[9];
            ar[8] = 1.0f;
            if (act) {
                cd = dsts[pp];
                int e = sorted[pp];
                int s = srcA[e];
                {
                    const float4* ap = (const float4*)(attrA + e * 8);
                    float4 v0 = ap[0], v1 = ap[1];
                    ar[0] = v0.x; ar[1] = v0.y; ar[2] = v0.z; ar[3] = v0.w;
                    ar[4] = v1.x; ar[5] = v1.y; ar[6] = v1.z; ar[7] = v1.w;
                }
                const float4* xp = (const float4*)(xsrc + s * 32);
                #pragma unroll
                for (int q = 0; q < 4; q++) {
                    float4 v0 = xp[2 * q], v1 = xp[2 * q + 1];
                    uint4 pk;
                    pk.x = pack_trunc(v0.x, v0.y);
                    pk.y = pack_trunc(v0.z, v0.w);
                    pk.z = pack_trunc(v1.x, v1.y);
                    pk.w = pack_trunc(v1.z, v1.w);
                    xstage[wave][q * 64 + lane] = pk;
                }
            }

            f32x4 zero4 = {0.f, 0.f, 0.f, 0.f};
            #pragma unroll
            for (int mtile = 0; mtile < 4; mtile++) {
                uint4 araw = xstage[wave][quad * 64 + mtile * 16 + (lane & 15)];
                short8 af = *(short8*)&araw;
                float mm0[4] = {0.f, 0.f, 0.f, 0.f};
                float mm1[4] = {0.f, 0.f, 0.f, 0.f};
                #pragma unroll
                for (int a = 0; a < 9; a++) {
                    f32x4 t0 = __builtin_amdgcn_mfma_f32_16x16x32_bf16(af, *(short8*)&bf[a][0], zero4, 0, 0, 0);
                    f32x4 t1 = __builtin_amdgcn_mfma_f32_16x16x32_bf16(af, *(short8*)&bf[a][1], zero4, 0, 0, 0);
                    #pragma unroll
                    for (int r = 0; r < 4; r++) {
                        int m = mtile * 16 + quad * 4 + r;
                        float av = __shfl(ar[a], m, 64);
                        mm0[r] = fmaf(av, t0[r], mm0[r]);
                        mm1[r] = fmaf(av, t1[r], mm1[r]);
                    }
                }
                #pragma unroll
                for (int r = 0; r < 4; r++) {
                    int row = wave * 64 + mtile * 16 + quad * 4 + r;
                    stage[row * 36 + (lane & 15)]      = mm0[r];
                    stage[row * 36 + 16 + (lane & 15)] = mm1[r];
                }
            }
            __syncthreads();

            bool head = act && (pp == blockStart || dsts[pp - 1] != cd);
            if (head) {
                float msg[32];
                const float4* rrow0 = (const float4*)(stage + tid * 36);
                #pragma unroll
                for (int j = 0; j < 8; j++) {
                    float4 v = rrow0[j];
                    msg[j * 4 + 0] = v.x; msg[j * 4 + 1] = v.y;
                    msg[j * 4 + 2] = v.z; msg[j * 4 + 3] = v.w;
                }
                int blockEnd = min(blockStart + 256, relEnd);
                int q = pp + 1;
                while (q < blockEnd && dsts[q] == cd) {
                    const float4* rrow = (const float4*)(stage + (q - blockStart) * 36);
                    #pragma unroll
                    for (int j = 0; j < 8; j++) {
                        float4 v = rrow[j];
                        msg[j * 4 + 0] += v.x; msg[j * 4 + 1] += v.y;
                        msg[j * 4 + 2] += v.z; msg[j * 4 + 3] += v.w;
                    }
                    q++;
                }
                bool openR = (q == blockEnd) && (q < TOTE) && (dsts[q] == cd);
                bool openL = (pp == blockStart) && (pp > 0) && (dsts[pp - 1] == cd);
                float* dp = acc + (size_t)cd * 32;
                if (openL || openR) {
                    #pragma unroll
                    for (int o = 0; o < 32; o++) atomicAdd(dp + o, msg[o]);
                } else {
                    float4* dp4 = (float4*)dp;
                    #pragma unroll
                    for (int j = 0; j < 8; j++)
                        dp4[j] = make_float4(msg[j * 4 + 0], msg[j * 4 + 1], msg[j * 4 + 2], msg[j * 4 + 3]);
                }
            }
            __syncthreads();                  // stage reuse across bv iterations
        }
    }
    __threadfence();
    grid.sync();

    // ================= P5: finish layer 1 (+root, sigmoid); layer-2 prep
    for (int i = gid; i < NB; i += gstride) {
        bool is_org = i >= NI;
        int n = is_org ? i - NI : i;
        const float* x    = is_org ? p.x_org : p.x_ind;
        const float* WrT  = ws + (is_org ? OFF_WRT_IO : OFF_WRT_OI);
        const float* bias = is_org ? p.b_io : p.b_oi;

        float xr[32];
        const float4* xp = (const float4*)(x + n * 32);
        #pragma unroll
        for (int q = 0; q < 8; q++) {
            float4 v = xp[q];
            xr[q * 4 + 0] = v.x; xr[q * 4 + 1] = v.y; xr[q * 4 + 2] = v.z; xr[q * 4 + 3] = v.w;
        }
        float h[32];
        const float4* aprow = (const float4*)(acc + (size_t)i * 32);
        #pragma unroll
        for (int q = 0; q < 8; q++) {
            float4 v = aprow[q];
            h[q * 4 + 0] = v.x; h[q * 4 + 1] = v.y; h[q * 4 + 2] = v.z; h[q * 4 + 3] = v.w;
        }
        #pragma unroll 4
        for (int o = 0; o < 32; o++) {
            float s = bias[o] + h[o];
            #pragma unroll
            for (int i2 = 0; i2 < 32; i2++) s = fmaf(xr[i2], WrT[o * 32 + i2], s);
            h[o] = sigmoidf_fast(s);
        }
        if (!is_org) {
            float s = p.b2[0];
            #pragma unroll
            for (int i2 = 0; i2 < 32; i2++) s = fmaf(h[i2], p.Wr2[i2], s);
            p.out[n] = s;                     // layer-2 root, pre-sigmoid
        } else {
            float z2 = 0.0f;
            #pragma unroll
            for (int i2 = 0; i2 < 32; i2++) z2 = fmaf(h[i2], p.bm2[i2], z2);
            float* yz = y2z2 + n * 12;
            yz[0] = z2;
            #pragma unroll
            for (int a = 0; a < 8; a++) {
                float s = 0.0f;
                #pragma unroll
                for (int i2 = 0; i2 < 32; i2++) s = fmaf(h[i2], p.Wm2[a * 32 + i2], s);
                yz[1 + a] = s;
            }
        }
    }
    __threadfence();
    grid.sync();

    // ================= P6: layer-2 CSR gather + final sigmoid
    for (int d = gid; d < NI; d += gstride) {
        int base = scanned[d] + blockpref[d >> 8];
        int next = scanned[d + 1] + blockpref[(d + 1) >> 8];
        float t = p.out[d];
        for (int q = base; q < next; q++) {
            int e = sorted[q];
            int s = p.src_oi[e];
            const float* yz = y2z2 + s * 12;
            const float4* ap = (const float4*)(p.attr_oi + e * 8);
            float4 a0 = ap[0], a1 = ap[1];
            float m = yz[0];
            m = fmaf(a0.x, yz[1], m); m = fmaf(a0.y, yz[2], m);
            m = fmaf(a0.z, yz[3], m); m = fmaf(a0.w, yz[4], m);
            m = fmaf(a1.x, yz[5], m); m = fmaf(a1.y, yz[6], m);
            m = fmaf(a1.z, yz[7], m); m = fmaf(a1.w, yz[8], m);
            t += m;
        }
        p.out[d] = sigmoidf_fast(t);
    }
}

// ---------------------------------------------------------------- launch
extern "C" void kernel_launch(void* const* d_in, const int* in_sizes, int n_in,
                              void* d_out, int out_size, void* d_ws, size_t ws_size,
                              hipStream_t stream)
{
    Params prm;
    prm.x_ind   = (const float*)d_in[0];
    prm.x_org   = (const float*)d_in[1];
    prm.src_oi  = (const int*)d_in[2];
    prm.dst_oi  = (const int*)d_in[3];
    prm.attr_oi = (const float*)d_in[4];
    prm.src_io  = (const int*)d_in[5];
    prm.dst_io  = (const int*)d_in[6];
    prm.attr_io = (const float*)d_in[7];
    prm.Wm_oi   = (const float*)d_in[8];
    prm.bm_oi   = (const float*)d_in[9];
    prm.Wr_oi   = (const float*)d_in[10];
    prm.b_oi    = (const float*)d_in[11];
    prm.Wm_io   = (const float*)d_in[12];
    prm.bm_io   = (const float*)d_in[13];
    prm.Wr_io   = (const float*)d_in[14];
    prm.b_io    = (const float*)d_in[15];
    prm.Wm2     = (const float*)d_in[16];
    prm.bm2     = (const float*)d_in[17];
    prm.Wr2     = (const float*)d_in[18];
    prm.b2      = (const float*)d_in[19];
    prm.ws      = (float*)d_ws;
    prm.out     = (float*)d_out;

    int nblk = 0;
    hipOccupancyMaxActiveBlocksPerMultiprocessor(&nblk, k_mega, 256, 0);
    if (nblk < 1) nblk = 1;
    int grid = nblk * 256;                 // 256 CUs on MI355X
    if (grid > 768) grid = 768;            // edge phase needs at most 782 virtual blocks
    if (grid < 256) grid = 256;

    void* kargs[] = { (void*)&prm };
    hipLaunchCooperativeKernel((void*)k_mega, dim3(grid), dim3(256), kargs, 0, stream);
}

// Round 7
// 166.618 us; speedup vs baseline: 3.6648x; 3.6648x over previous
//
#include <hip/hip_runtime.h>
#include <math.h>

#define NI 100000
#define NO 50000
#define NE 100000
#define NB (NI + NO)          // 150000 combined dst bins
#define TOTE (2 * NE)         // 200000

// ---- ws layout (4B units) ----
#define OFF_WFRAG   0         // 9216 dwords = 2304 uint4
#define OFF_Y2Z2    9216      // 600000
#define OFF_HEAD    609216    // 150016 ints
#define OFF_NXT     759232    // 200000 ints
#define OFF_MSG     959232    // 6400000 floats (TOTE x 32), 16B-aligned
// total ~29.4 MB

static constexpr int B_EDGE = (NE + 255) / 256;        // 391
static constexpr int B_IND  = (NI + 255) / 256;        // 391
static constexpr int B_ORG  = (NO + 255) / 256;        // 196
static constexpr int B_INIT = (NB + 2304 + 255) / 256; // 596

typedef __attribute__((ext_vector_type(8))) short short8;
typedef __attribute__((ext_vector_type(4))) float f32x4;

__device__ __forceinline__ float sigmoidf_fast(float x) {
    return 1.0f / (1.0f + __expf(-x));
}
__device__ __forceinline__ unsigned f2bf(float f) {   // RTNE to bf16
    unsigned u = __float_as_uint(f);
    return (u + 0x7FFFu + ((u >> 16) & 1u)) >> 16;
}
__device__ __forceinline__ unsigned pack_trunc(float lo, float hi) {
    return __builtin_amdgcn_perm(__float_as_uint(hi), __float_as_uint(lo), 0x07060302u);
}

// ---------------------------------------------------------------- init: head=-1 + MFMA B-frag prep
__global__ __launch_bounds__(256) void k_init(
    const float* __restrict__ Wm_oi, const float* __restrict__ bm_oi,
    const float* __restrict__ Wm_io, const float* __restrict__ bm_io,
    float* __restrict__ ws)
{
    int idx = blockIdx.x * 256 + threadIdx.x;
    int* head = (int*)(ws + OFF_HEAD);
    if (idx < NB) {
        head[idx] = -1;
    } else {
        int u = idx - NB;                    // [0, 2304)
        if (u >= 2304) return;
        int rel = u >= 1152;                 // 0 = oi, 1 = io
        int v = u - rel * 1152;
        int lane = v & 63;
        int fi = v >> 6;                     // 0..17
        int a = fi >> 1;                     // 0..8
        int nt = fi & 1;
        int quad = lane >> 4;
        int n = nt * 16 + (lane & 15);
        const float* Wm = rel ? Wm_io : Wm_oi;
        const float* bm = rel ? bm_io : bm_oi;
        unsigned pk[4];
        #pragma unroll
        for (int d = 0; d < 4; d++) {
            int k0 = quad * 8 + 2 * d;
            float vlo = (a < 8) ? Wm[a * 1024 + k0 * 32 + n]       : bm[k0 * 32 + n];
            float vhi = (a < 8) ? Wm[a * 1024 + (k0 + 1) * 32 + n] : bm[(k0 + 1) * 32 + n];
            pk[d] = f2bf(vlo) | (f2bf(vhi) << 16);
        }
        uint4* wf = (uint4*)(ws + OFF_WFRAG);
        wf[((rel * 9 + a) * 2 + nt) * 64 + lane] = make_uint4(pk[0], pk[1], pk[2], pk[3]);
    }
}

// ---------------------------------------------------------------- edge messages via MFMA + list build
__global__ __launch_bounds__(256) void k_msg(
    const int* __restrict__ src_oi, const int* __restrict__ dst_oi, const float* __restrict__ attr_oi,
    const int* __restrict__ src_io, const int* __restrict__ dst_io, const float* __restrict__ attr_io,
    const float* __restrict__ x_ind, const float* __restrict__ x_org,
    float* __restrict__ ws)
{
    __shared__ uint4 xstage[4][256];      // 16 KB, bf16 x rows
    __shared__ float stage[256 * 36];     // 36 KB msg staging

    int* head  = (int*)(ws + OFF_HEAD);
    int* nxt   = (int*)(ws + OFF_NXT);
    float* msg = ws + OFF_MSG;

    bool is_io = blockIdx.x >= B_EDGE;
    int blockStart = is_io ? (NE + ((int)blockIdx.x - B_EDGE) * 256) : ((int)blockIdx.x * 256);
    int relEnd = is_io ? TOTE : NE;
    int tid = threadIdx.x;
    int wave = tid >> 6, lane = tid & 63, quad = lane >> 4;
    int p = blockStart + tid;              // global edge-slot (also msg row)
    bool act = p < relEnd;
    int e = p - (is_io ? NE : 0);          // relation-local edge id

    const int*   srcA  = is_io ? src_io : src_oi;
    const int*   dstA  = is_io ? dst_io : dst_oi;
    const float* attrA = is_io ? attr_io : attr_oi;
    const float* xsrc  = is_io ? x_ind : x_org;

    const uint4* wfr = ((const uint4*)(ws + OFF_WFRAG)) + (is_io ? 1152 : 0);
    uint4 bf[9][2];
    #pragma unroll
    for (int a = 0; a < 9; a++) {
        #pragma unroll
        for (int nt = 0; nt < 2; nt++)
            bf[a][nt] = wfr[((a * 2 + nt) * 64) + lane];
    }

    float ar[9];
    ar[8] = 1.0f;
    if (act) {
        int s = srcA[e];
        {
            const float4* ap = (const float4*)(attrA + e * 8);
            float4 v0 = ap[0], v1 = ap[1];
            ar[0] = v0.x; ar[1] = v0.y; ar[2] = v0.z; ar[3] = v0.w;
            ar[4] = v1.x; ar[5] = v1.y; ar[6] = v1.z; ar[7] = v1.w;
        }
        const float4* xp = (const float4*)(xsrc + s * 32);
        #pragma unroll
        for (int q = 0; q < 4; q++) {
            float4 v0 = xp[2 * q], v1 = xp[2 * q + 1];
            uint4 pk;
            pk.x = pack_trunc(v0.x, v0.y);
            pk.y = pack_trunc(v0.z, v0.w);
            pk.z = pack_trunc(v1.x, v1.y);
            pk.w = pack_trunc(v1.z, v1.w);
            xstage[wave][q * 64 + lane] = pk;
        }
        // linked-list insert (traversed only in later kernels)
        int cd = is_io ? (NI + dstA[e]) : dstA[e];
        int old = atomicExch(&head[cd], p);
        nxt[p] = old;
    }

    f32x4 zero4 = {0.f, 0.f, 0.f, 0.f};
    #pragma unroll
    for (int mtile = 0; mtile < 4; mtile++) {
        uint4 araw = xstage[wave][quad * 64 + mtile * 16 + (lane & 15)];
        short8 af = *(short8*)&araw;
        float mm0[4] = {0.f, 0.f, 0.f, 0.f};
        float mm1[4] = {0.f, 0.f, 0.f, 0.f};
        #pragma unroll
        for (int a = 0; a < 9; a++) {
            f32x4 t0 = __builtin_amdgcn_mfma_f32_16x16x32_bf16(af, *(short8*)&bf[a][0], zero4, 0, 0, 0);
            f32x4 t1 = __builtin_amdgcn_mfma_f32_16x16x32_bf16(af, *(short8*)&bf[a][1], zero4, 0, 0, 0);
            #pragma unroll
            for (int r = 0; r < 4; r++) {
                int m = mtile * 16 + quad * 4 + r;
                float av = __shfl(ar[a], m, 64);
                mm0[r] = fmaf(av, t0[r], mm0[r]);
                mm1[r] = fmaf(av, t1[r], mm1[r]);
            }
        }
        #pragma unroll
        for (int r = 0; r < 4; r++) {
            int row = wave * 64 + mtile * 16 + quad * 4 + r;
            stage[row * 36 + (lane & 15)]      = mm0[r];
            stage[row * 36 + 16 + (lane & 15)] = mm1[r];
        }
    }
    __syncthreads();

    // coalesced dense msg-row write (128 B per edge)
    if (act) {
        const float4* srow = (const float4*)(stage + tid * 36);
        float4* mrow = (float4*)(msg + (size_t)p * 32);
        #pragma unroll
        for (int j = 0; j < 8; j++) mrow[j] = srow[j];
    }
}

// ---------------------------------------------------------------- org nodes: walk list, finish L1, prep L2
__global__ __launch_bounds__(256) void k_org(
    const float* __restrict__ x_org, const float* __restrict__ ws,
    const float* __restrict__ Wr_io, const float* __restrict__ b_io,
    const float* __restrict__ Wm2, const float* __restrict__ bm2,
    float* __restrict__ y2z2)
{
    int n = blockIdx.x * 256 + threadIdx.x;
    if (n >= NO) return;
    const int* head  = (const int*)(ws + OFF_HEAD);
    const int* nxt   = (const int*)(ws + OFF_NXT);
    const float* msg = ws + OFF_MSG;

    float ms[32];
    #pragma unroll
    for (int o = 0; o < 32; o++) ms[o] = 0.0f;
    for (int e = head[NI + n]; e != -1; e = nxt[e]) {
        const float4* mr = (const float4*)(msg + (size_t)e * 32);
        #pragma unroll
        for (int j = 0; j < 8; j++) {
            float4 v = mr[j];
            ms[j * 4 + 0] += v.x; ms[j * 4 + 1] += v.y;
            ms[j * 4 + 2] += v.z; ms[j * 4 + 3] += v.w;
        }
    }
    float xr[32];
    const float4* xp = (const float4*)(x_org + n * 32);
    #pragma unroll
    for (int q = 0; q < 8; q++) {
        float4 v = xp[q];
        xr[q * 4 + 0] = v.x; xr[q * 4 + 1] = v.y; xr[q * 4 + 2] = v.z; xr[q * 4 + 3] = v.w;
    }
    float h[32];
    #pragma unroll 4
    for (int o = 0; o < 32; o++) {
        float s = b_io[o] + ms[o];
        #pragma unroll
        for (int i = 0; i < 32; i++) s = fmaf(xr[i], Wr_io[i * 32 + o], s);   // wave-uniform -> s_load
        h[o] = sigmoidf_fast(s);
    }
    float z2 = 0.0f;
    #pragma unroll
    for (int i = 0; i < 32; i++) z2 = fmaf(h[i], bm2[i], z2);
    float* yz = y2z2 + n * 12;
    yz[0] = z2;
    #pragma unroll
    for (int a = 0; a < 8; a++) {
        float s = 0.0f;
        #pragma unroll
        for (int i = 0; i < 32; i++) s = fmaf(h[i], Wm2[a * 32 + i], s);
        yz[1 + a] = s;
    }
}

// ---------------------------------------------------------------- indivi nodes: single walk (L1 sum + L2 msg), finish, out
__global__ __launch_bounds__(256) void k_out(
    const float* __restrict__ x_ind, const float* __restrict__ ws,
    const float* __restrict__ Wr_oi, const float* __restrict__ b_oi,
    const int* __restrict__ src_oi, const float* __restrict__ attr_oi,
    const float* __restrict__ Wr2, const float* __restrict__ b2,
    const float* __restrict__ y2z2,
    float* __restrict__ out)
{
    int d = blockIdx.x * 256 + threadIdx.x;
    if (d >= NI) return;
    const int* head  = (const int*)(ws + OFF_HEAD);
    const int* nxt   = (const int*)(ws + OFF_NXT);
    const float* msg = ws + OFF_MSG;

    float ms[32];
    #pragma unroll
    for (int o = 0; o < 32; o++) ms[o] = 0.0f;
    float m2acc = 0.0f;
    for (int e = head[d]; e != -1; e = nxt[e]) {
        const float4* mr = (const float4*)(msg + (size_t)e * 32);
        #pragma unroll
        for (int j = 0; j < 8; j++) {
            float4 v = mr[j];
            ms[j * 4 + 0] += v.x; ms[j * 4 + 1] += v.y;
            ms[j * 4 + 2] += v.z; ms[j * 4 + 3] += v.w;
        }
        // layer-2 message for this edge (e < NE, oi relation)
        int s = src_oi[e];
        const float* yz = y2z2 + s * 12;
        const float4* ap = (const float4*)(attr_oi + e * 8);
        float4 a0 = ap[0], a1 = ap[1];
        float m = yz[0];
        m = fmaf(a0.x, yz[1], m); m = fmaf(a0.y, yz[2], m);
        m = fmaf(a0.z, yz[3], m); m = fmaf(a0.w, yz[4], m);
        m = fmaf(a1.x, yz[5], m); m = fmaf(a1.y, yz[6], m);
        m = fmaf(a1.z, yz[7], m); m = fmaf(a1.w, yz[8], m);
        m2acc += m;
    }
    float xr[32];
    const float4* xp = (const float4*)(x_ind + d * 32);
    #pragma unroll
    for (int q = 0; q < 8; q++) {
        float4 v = xp[q];
        xr[q * 4 + 0] = v.x; xr[q * 4 + 1] = v.y; xr[q * 4 + 2] = v.z; xr[q * 4 + 3] = v.w;
    }
    float t = b2[0] + m2acc;
    #pragma unroll 4
    for (int o = 0; o < 32; o++) {
        float s = b_oi[o] + ms[o];
        #pragma unroll
        for (int i = 0; i < 32; i++) s = fmaf(xr[i], Wr_oi[i * 32 + o], s);   // wave-uniform -> s_load
        t = fmaf(sigmoidf_fast(s), Wr2[o], t);
    }
    out[d] = sigmoidf_fast(t);
}

// ---------------------------------------------------------------- launch
extern "C" void kernel_launch(void* const* d_in, const int* in_sizes, int n_in,
                              void* d_out, int out_size, void* d_ws, size_t ws_size,
                              hipStream_t stream)
{
    const float* x_ind   = (const float*)d_in[0];
    const float* x_org   = (const float*)d_in[1];
    const int*   src_oi  = (const int*)d_in[2];
    const int*   dst_oi  = (const int*)d_in[3];
    const float* attr_oi = (const float*)d_in[4];
    const int*   src_io  = (const int*)d_in[5];
    const int*   dst_io  = (const int*)d_in[6];
    const float* attr_io = (const float*)d_in[7];
    const float* Wm_oi   = (const float*)d_in[8];
    const float* bm_oi   = (const float*)d_in[9];
    const float* Wr_oi   = (const float*)d_in[10];
    const float* b_oi    = (const float*)d_in[11];
    const float* Wm_io   = (const float*)d_in[12];
    const float* bm_io   = (const float*)d_in[13];
    const float* Wr_io   = (const float*)d_in[14];
    const float* b_io    = (const float*)d_in[15];
    const float* Wm2     = (const float*)d_in[16];
    const float* bm2     = (const float*)d_in[17];
    const float* Wr2     = (const float*)d_in[18];
    const float* b2      = (const float*)d_in[19];

    float* ws   = (float*)d_ws;
    float* y2z2 = ws + OFF_Y2Z2;
    float* out  = (float*)d_out;

    k_init<<<B_INIT, 256, 0, stream>>>(Wm_oi, bm_oi, Wm_io, bm_io, ws);

    k_msg<<<2 * B_EDGE, 256, 0, stream>>>(
        src_oi, dst_oi, attr_oi, src_io, dst_io, attr_io, x_ind, x_org, ws);

    k_org<<<B_ORG, 256, 0, stream>>>(
        x_org, ws, Wr_io, b_io, Wm2, bm2, y2z2);

    k_out<<<B_IND, 256, 0, stream>>>(
        x_ind, ws, Wr_oi, b_oi, src_oi, attr_oi, Wr2, b2, y2z2, out);
}

// Round 8
// 163.158 us; speedup vs baseline: 3.7425x; 1.0212x over previous
//
#include <hip/hip_runtime.h>
#include <math.h>

#define NI 100000
#define NO 50000
#define NE 100000
#define NB (NI + NO)          // 150000 combined dst bins
#define TOTE (2 * NE)         // 200000

// ---- ws layout (4B units) ----
#define OFF_WFRAG   0         // 9216 dwords = 2304 uint4
#define OFF_Y2Z2    9216      // 600000
#define OFF_HEAD    609216    // 150016 ints
#define OFF_NXT     759232    // 200000 ints
#define OFF_MSG     959232    // 6400000 floats (TOTE x 32), 16B-aligned
// total ~29.4 MB

static constexpr int B_EDGE = (NE + 255) / 256;        // 391
static constexpr int B_IND  = (NI + 255) / 256;        // 391
static constexpr int B_ORG  = (NO + 255) / 256;        // 196
static constexpr int B_INIT = (NB + 2304 + 255) / 256; // 596

typedef __attribute__((ext_vector_type(8))) short short8;
typedef __attribute__((ext_vector_type(4))) float f32x4;

__device__ __forceinline__ float sigmoidf_fast(float x) {
    return 1.0f / (1.0f + __expf(-x));
}
__device__ __forceinline__ unsigned f2bf(float f) {   // RTNE to bf16
    unsigned u = __float_as_uint(f);
    return (u + 0x7FFFu + ((u >> 16) & 1u)) >> 16;
}
__device__ __forceinline__ unsigned pack_trunc(float lo, float hi) {
    return __builtin_amdgcn_perm(__float_as_uint(hi), __float_as_uint(lo), 0x07060302u);
}

// ---------------------------------------------------------------- init: head=-1 + MFMA weight-frag prep
// Frag layout (16x16x32 bf16, verified R4): lane&15 = non-K index (here: o),
// quad = K-chunk (k = quad*8 + j, bf16 pairs packed (k,k+1) per dword).
// Identical per-lane structure for A- and B-operand roles -> reusable as A.
__global__ __launch_bounds__(256) void k_init(
    const float* __restrict__ Wm_oi, const float* __restrict__ bm_oi,
    const float* __restrict__ Wm_io, const float* __restrict__ bm_io,
    float* __restrict__ ws)
{
    int idx = blockIdx.x * 256 + threadIdx.x;
    int* head = (int*)(ws + OFF_HEAD);
    if (idx < NB) {
        head[idx] = -1;
    } else {
        int u = idx - NB;                    // [0, 2304)
        if (u >= 2304) return;
        int rel = u >= 1152;                 // 0 = oi, 1 = io
        int v = u - rel * 1152;
        int lane = v & 63;
        int fi = v >> 6;                     // 0..17
        int a = fi >> 1;                     // 0..8
        int nt = fi & 1;
        int quad = lane >> 4;
        int n = nt * 16 + (lane & 15);       // output index o
        const float* Wm = rel ? Wm_io : Wm_oi;
        const float* bm = rel ? bm_io : bm_oi;
        unsigned pk[4];
        #pragma unroll
        for (int d = 0; d < 4; d++) {
            int k0 = quad * 8 + 2 * d;
            float vlo = (a < 8) ? Wm[a * 1024 + k0 * 32 + n]       : bm[k0 * 32 + n];
            float vhi = (a < 8) ? Wm[a * 1024 + (k0 + 1) * 32 + n] : bm[(k0 + 1) * 32 + n];
            pk[d] = f2bf(vlo) | (f2bf(vhi) << 16);
        }
        uint4* wf = (uint4*)(ws + OFF_WFRAG);
        wf[((rel * 9 + a) * 2 + nt) * 64 + lane] = make_uint4(pk[0], pk[1], pk[2], pk[3]);
    }
}

// ---------------------------------------------------------------- edge messages via MFMA (swapped operands) + list build
__global__ __launch_bounds__(256) void k_msg(
    const int* __restrict__ src_oi, const int* __restrict__ dst_oi, const float* __restrict__ attr_oi,
    const int* __restrict__ src_io, const int* __restrict__ dst_io, const float* __restrict__ attr_io,
    const float* __restrict__ x_ind, const float* __restrict__ x_org,
    float* __restrict__ ws)
{
    __shared__ uint4 xstage[4][256];      // 16 KB only: [wave][kchunk*64 + wave-local edge]

    int* head  = (int*)(ws + OFF_HEAD);
    int* nxt   = (int*)(ws + OFF_NXT);
    float* msg = ws + OFF_MSG;

    bool is_io = blockIdx.x >= B_EDGE;
    int blockStart = is_io ? (NE + ((int)blockIdx.x - B_EDGE) * 256) : ((int)blockIdx.x * 256);
    int relEnd = is_io ? TOTE : NE;
    int tid = threadIdx.x;
    int wave = tid >> 6, lane = tid & 63, quad = lane >> 4;
    int p = blockStart + tid;              // own global edge-slot (also msg row)
    bool act = p < relEnd;
    int e = p - (is_io ? NE : 0);          // relation-local edge id

    const int*   srcA  = is_io ? src_io : src_oi;
    const int*   dstA  = is_io ? dst_io : dst_oi;
    const float* attrA = is_io ? attr_io : attr_oi;
    const float* xsrc  = is_io ? x_ind : x_org;

    // weight fragments (now the A operand: m = o)
    const uint4* wfr = ((const uint4*)(ws + OFF_WFRAG)) + (is_io ? 1152 : 0);
    uint4 wf[9][2];
    #pragma unroll
    for (int a = 0; a < 9; a++) {
        #pragma unroll
        for (int nt = 0; nt < 2; nt++)
            wf[a][nt] = wfr[((a * 2 + nt) * 64) + lane];
    }

    float ar[9];
    ar[8] = 1.0f;
    if (act) {
        int s = srcA[e];
        {
            const float4* ap = (const float4*)(attrA + e * 8);
            float4 v0 = ap[0], v1 = ap[1];
            ar[0] = v0.x; ar[1] = v0.y; ar[2] = v0.z; ar[3] = v0.w;
            ar[4] = v1.x; ar[5] = v1.y; ar[6] = v1.z; ar[7] = v1.w;
        }
        const float4* xp = (const float4*)(xsrc + s * 32);
        #pragma unroll
        for (int q = 0; q < 4; q++) {
            float4 v0 = xp[2 * q], v1 = xp[2 * q + 1];
            uint4 pk;
            pk.x = pack_trunc(v0.x, v0.y);
            pk.y = pack_trunc(v0.z, v0.w);
            pk.z = pack_trunc(v1.x, v1.y);
            pk.w = pack_trunc(v1.z, v1.w);
            xstage[wave][q * 64 + lane] = pk;
        }
        // linked-list insert (traversed in later kernels)
        int cd = is_io ? (NI + dstA[e]) : dstA[e];
        int old = atomicExch(&head[cd], p);
        nxt[p] = old;
    }
    // within-wave LDS visibility: compiler inserts lgkmcnt waits

    f32x4 zero4 = {0.f, 0.f, 0.f, 0.f};
    #pragma unroll
    for (int mtile = 0; mtile < 4; mtile++) {
        // B-frag: B[k=quad*8+j][n=lane&15] = x of edge (wave-local) mtile*16+(lane&15)
        uint4 braw = xstage[wave][quad * 64 + mtile * 16 + (lane & 15)];
        short8 bx = *(short8*)&braw;
        float mm0[4] = {0.f, 0.f, 0.f, 0.f};
        float mm1[4] = {0.f, 0.f, 0.f, 0.f};
        #pragma unroll
        for (int a = 0; a < 9; a++) {
            // D[m=o][n=edge]: col = edge = lane&15 -> attr is per-lane-constant
            f32x4 t0 = __builtin_amdgcn_mfma_f32_16x16x32_bf16(*(short8*)&wf[a][0], bx, zero4, 0, 0, 0);
            f32x4 t1 = __builtin_amdgcn_mfma_f32_16x16x32_bf16(*(short8*)&wf[a][1], bx, zero4, 0, 0, 0);
            float av = __shfl(ar[a], mtile * 16 + (lane & 15), 64);
            #pragma unroll
            for (int r = 0; r < 4; r++) {
                mm0[r] = fmaf(av, t0[r], mm0[r]);
                mm1[r] = fmaf(av, t1[r], mm1[r]);
            }
        }
        // direct dense store: rows o = nt*16 + quad*4 + r of edge-col ecol
        int ecol = blockStart + wave * 64 + mtile * 16 + (lane & 15);
        if (ecol < relEnd) {
            float* mrow = msg + (size_t)ecol * 32 + quad * 4;
            *(f32x4*)(mrow)      = *(f32x4*)mm0;
            *(f32x4*)(mrow + 16) = *(f32x4*)mm1;
        }
    }
}

// ---------------------------------------------------------------- org nodes: walk list, finish L1, prep L2
__global__ __launch_bounds__(256) void k_org(
    const float* __restrict__ x_org, const float* __restrict__ ws,
    const float* __restrict__ Wr_io, const float* __restrict__ b_io,
    const float* __restrict__ Wm2, const float* __restrict__ bm2,
    float* __restrict__ y2z2)
{
    int n = blockIdx.x * 256 + threadIdx.x;
    if (n >= NO) return;
    const int* head  = (const int*)(ws + OFF_HEAD);
    const int* nxt   = (const int*)(ws + OFF_NXT);
    const float* msg = ws + OFF_MSG;

    float ms[32];
    #pragma unroll
    for (int o = 0; o < 32; o++) ms[o] = 0.0f;
    for (int e = head[NI + n]; e != -1; e = nxt[e]) {
        const float4* mr = (const float4*)(msg + (size_t)e * 32);
        #pragma unroll
        for (int j = 0; j < 8; j++) {
            float4 v = mr[j];
            ms[j * 4 + 0] += v.x; ms[j * 4 + 1] += v.y;
            ms[j * 4 + 2] += v.z; ms[j * 4 + 3] += v.w;
        }
    }
    float xr[32];
    const float4* xp = (const float4*)(x_org + n * 32);
    #pragma unroll
    for (int q = 0; q < 8; q++) {
        float4 v = xp[q];
        xr[q * 4 + 0] = v.x; xr[q * 4 + 1] = v.y; xr[q * 4 + 2] = v.z; xr[q * 4 + 3] = v.w;
    }
    float h[32];
    #pragma unroll 4
    for (int o = 0; o < 32; o++) {
        float s = b_io[o] + ms[o];
        #pragma unroll
        for (int i = 0; i < 32; i++) s = fmaf(xr[i], Wr_io[i * 32 + o], s);   // wave-uniform -> s_load
        h[o] = sigmoidf_fast(s);
    }
    float z2 = 0.0f;
    #pragma unroll
    for (int i = 0; i < 32; i++) z2 = fmaf(h[i], bm2[i], z2);
    float* yz = y2z2 + n * 12;
    yz[0] = z2;
    #pragma unroll
    for (int a = 0; a < 8; a++) {
        float s = 0.0f;
        #pragma unroll
        for (int i = 0; i < 32; i++) s = fmaf(h[i], Wm2[a * 32 + i], s);
        yz[1 + a] = s;
    }
}

// ---------------------------------------------------------------- indivi nodes: single walk (L1 sum + L2 msg), finish, out
__global__ __launch_bounds__(256) void k_out(
    const float* __restrict__ x_ind, const float* __restrict__ ws,
    const float* __restrict__ Wr_oi, const float* __restrict__ b_oi,
    const int* __restrict__ src_oi, const float* __restrict__ attr_oi,
    const float* __restrict__ Wr2, const float* __restrict__ b2,
    const float* __restrict__ y2z2,
    float* __restrict__ out)
{
    int d = blockIdx.x * 256 + threadIdx.x;
    if (d >= NI) return;
    const int* head  = (const int*)(ws + OFF_HEAD);
    const int* nxt   = (const int*)(ws + OFF_NXT);
    const float* msg = ws + OFF_MSG;

    float ms[32];
    #pragma unroll
    for (int o = 0; o < 32; o++) ms[o] = 0.0f;
    float m2acc = 0.0f;
    for (int e = head[d]; e != -1; e = nxt[e]) {
        const float4* mr = (const float4*)(msg + (size_t)e * 32);
        #pragma unroll
        for (int j = 0; j < 8; j++) {
            float4 v = mr[j];
            ms[j * 4 + 0] += v.x; ms[j * 4 + 1] += v.y;
            ms[j * 4 + 2] += v.z; ms[j * 4 + 3] += v.w;
        }
        // layer-2 message for this edge (e < NE, oi relation)
        int s = src_oi[e];
        const float* yz = y2z2 + s * 12;
        const float4* ap = (const float4*)(attr_oi + e * 8);
        float4 a0 = ap[0], a1 = ap[1];
        float m = yz[0];
        m = fmaf(a0.x, yz[1], m); m = fmaf(a0.y, yz[2], m);
        m = fmaf(a0.z, yz[3], m); m = fmaf(a0.w, yz[4], m);
        m = fmaf(a1.x, yz[5], m); m = fmaf(a1.y, yz[6], m);
        m = fmaf(a1.z, yz[7], m); m = fmaf(a1.w, yz[8], m);
        m2acc += m;
    }
    float xr[32];
    const float4* xp = (const float4*)(x_ind + d * 32);
    #pragma unroll
    for (int q = 0; q < 8; q++) {
        float4 v = xp[q];
        xr[q * 4 + 0] = v.x; xr[q * 4 + 1] = v.y; xr[q * 4 + 2] = v.z; xr[q * 4 + 3] = v.w;
    }
    float t = b2[0] + m2acc;
    #pragma unroll 4
    for (int o = 0; o < 32; o++) {
        float s = b_oi[o] + ms[o];
        #pragma unroll
        for (int i = 0; i < 32; i++) s = fmaf(xr[i], Wr_oi[i * 32 + o], s);   // wave-uniform -> s_load
        t = fmaf(sigmoidf_fast(s), Wr2[o], t);
    }
    out[d] = sigmoidf_fast(t);
}

// ---------------------------------------------------------------- launch
extern "C" void kernel_launch(void* const* d_in, const int* in_sizes, int n_in,
                              void* d_out, int out_size, void* d_ws, size_t ws_size,
                              hipStream_t stream)
{
    const float* x_ind   = (const float*)d_in[0];
    const float* x_org   = (const float*)d_in[1];
    const int*   src_oi  = (const int*)d_in[2];
    const int*   dst_oi  = (const int*)d_in[3];
    const float* attr_oi = (const float*)d_in[4];
    const int*   src_io  = (const int*)d_in[5];
    const int*   dst_io  = (const int*)d_in[6];
    const float* attr_io = (const float*)d_in[7];
    const float* Wm_oi   = (const float*)d_in[8];
    const float* bm_oi   = (const float*)d_in[9];
    const float* Wr_oi   = (const float*)d_in[10];
    const float* b_oi    = (const float*)d_in[11];
    const float* Wm_io   = (const float*)d_in[12];
    const float* bm_io   = (const float*)d_in[13];
    const float* Wr_io   = (const float*)d_in[14];
    const float* b_io    = (const float*)d_in[15];
    const float* Wm2     = (const float*)d_in[16];
    const float* bm2     = (const float*)d_in[17];
    const float* Wr2     = (const float*)d_in[18];
    const float* b2      = (const float*)d_in[19];

    float* ws   = (float*)d_ws;
    float* y2z2 = ws + OFF_Y2Z2;
    float* out  = (float*)d_out;

    k_init<<<B_INIT, 256, 0, stream>>>(Wm_oi, bm_oi, Wm_io, bm_io, ws);

    k_msg<<<2 * B_EDGE, 256, 0, stream>>>(
        src_oi, dst_oi, attr_oi, src_io, dst_io, attr_io, x_ind, x_org, ws);

    k_org<<<B_ORG, 256, 0, stream>>>(
        x_org, ws, Wr_io, b_io, Wm2, bm2, y2z2);

    k_out<<<B_IND, 256, 0, stream>>>(
        x_ind, ws, Wr_oi, b_oi, src_oi, attr_oi, Wr2, b2, y2z2, out);
}

// Round 9
// 161.741 us; speedup vs baseline: 3.7753x; 1.0088x over previous
//
#include <hip/hip_runtime.h>
#include <math.h>

#define NI 100000
#define NO 50000
#define NE 100000
#define NB (NI + NO)          // 150000 combined dst bins
#define TOTE (2 * NE)         // 200000

// ---- ws layout (4B units) ----
#define OFF_WFRAG   0         // 9216 dwords = 2304 uint4
#define OFF_Y2Z2    9216      // 600000
#define OFF_HEAD    609216    // 150016 ints
#define OFF_NXT     759232    // 200000 ints
#define OFF_MSG     959232    // bf16 msg: TOTE x 32 ushort = 3200000 float-slots
// total ~16.6 MB

static constexpr int B_EDGE = (NE + 255) / 256;        // 391
static constexpr int B_IND  = (NI + 255) / 256;        // 391
static constexpr int B_ORG  = (NO + 255) / 256;        // 196
static constexpr int B_INIT = (NB + 2304 + 255) / 256; // 596

typedef __attribute__((ext_vector_type(8))) short short8;
typedef __attribute__((ext_vector_type(4))) float f32x4;

__device__ __forceinline__ float sigmoidf_fast(float x) {
    return 1.0f / (1.0f + __expf(-x));
}
__device__ __forceinline__ unsigned f2bf(float f) {   // RTNE to bf16 (low 16 bits)
    unsigned u = __float_as_uint(f);
    return (u + 0x7FFFu + ((u >> 16) & 1u)) >> 16;
}
__device__ __forceinline__ float bflo(unsigned u) { return __uint_as_float(u << 16); }
__device__ __forceinline__ float bfhi(unsigned u) { return __uint_as_float(u & 0xFFFF0000u); }
__device__ __forceinline__ unsigned pack_trunc(float lo, float hi) {
    return __builtin_amdgcn_perm(__float_as_uint(hi), __float_as_uint(lo), 0x07060302u);
}

// ---------------------------------------------------------------- init: head=-1 + MFMA weight-frag prep
// Frag layout (16x16x32 bf16, verified R4/R8): lane&15 = non-K index,
// quad = K-chunk (k = quad*8 + j, bf16 pairs (k,k+1) per dword).
__global__ __launch_bounds__(256) void k_init(
    const float* __restrict__ Wm_oi, const float* __restrict__ bm_oi,
    const float* __restrict__ Wm_io, const float* __restrict__ bm_io,
    float* __restrict__ ws)
{
    int idx = blockIdx.x * 256 + threadIdx.x;
    int* head = (int*)(ws + OFF_HEAD);
    if (idx < NB) {
        head[idx] = -1;
    } else {
        int u = idx - NB;                    // [0, 2304)
        if (u >= 2304) return;
        int rel = u >= 1152;                 // 0 = oi, 1 = io
        int v = u - rel * 1152;
        int lane = v & 63;
        int fi = v >> 6;                     // 0..17
        int a = fi >> 1;                     // 0..8
        int nt = fi & 1;
        int quad = lane >> 4;
        int n = nt * 16 + (lane & 15);       // output index o
        const float* Wm = rel ? Wm_io : Wm_oi;
        const float* bm = rel ? bm_io : bm_oi;
        unsigned pk[4];
        #pragma unroll
        for (int d = 0; d < 4; d++) {
            int k0 = quad * 8 + 2 * d;
            float vlo = (a < 8) ? Wm[a * 1024 + k0 * 32 + n]       : bm[k0 * 32 + n];
            float vhi = (a < 8) ? Wm[a * 1024 + (k0 + 1) * 32 + n] : bm[(k0 + 1) * 32 + n];
            pk[d] = f2bf(vlo) | (f2bf(vhi) << 16);
        }
        uint4* wf = (uint4*)(ws + OFF_WFRAG);
        wf[((rel * 9 + a) * 2 + nt) * 64 + lane] = make_uint4(pk[0], pk[1], pk[2], pk[3]);
    }
}

// ---------------------------------------------------------------- edge messages via MFMA (swapped operands) + list build
__global__ __launch_bounds__(256) void k_msg(
    const int* __restrict__ src_oi, const int* __restrict__ dst_oi, const float* __restrict__ attr_oi,
    const int* __restrict__ src_io, const int* __restrict__ dst_io, const float* __restrict__ attr_io,
    const float* __restrict__ x_ind, const float* __restrict__ x_org,
    float* __restrict__ ws)
{
    __shared__ uint4 xstage[4][256];      // 16 KB: [wave][kchunk*64 + wave-local edge]

    int* head = (int*)(ws + OFF_HEAD);
    int* nxt  = (int*)(ws + OFF_NXT);
    unsigned short* msgb = (unsigned short*)(ws + OFF_MSG);

    bool is_io = blockIdx.x >= B_EDGE;
    int blockStart = is_io ? (NE + ((int)blockIdx.x - B_EDGE) * 256) : ((int)blockIdx.x * 256);
    int relEnd = is_io ? TOTE : NE;
    int tid = threadIdx.x;
    int wave = tid >> 6, lane = tid & 63, quad = lane >> 4;
    int p = blockStart + tid;              // own global edge-slot (also msg row)
    bool act = p < relEnd;
    int e = p - (is_io ? NE : 0);          // relation-local edge id

    const int*   srcA  = is_io ? src_io : src_oi;
    const int*   dstA  = is_io ? dst_io : dst_oi;
    const float* attrA = is_io ? attr_io : attr_oi;
    const float* xsrc  = is_io ? x_ind : x_org;

    // weight fragments (A operand: m = o)
    const uint4* wfr = ((const uint4*)(ws + OFF_WFRAG)) + (is_io ? 1152 : 0);
    uint4 wf[9][2];
    #pragma unroll
    for (int a = 0; a < 9; a++) {
        #pragma unroll
        for (int nt = 0; nt < 2; nt++)
            wf[a][nt] = wfr[((a * 2 + nt) * 64) + lane];
    }

    float ar[9];
    ar[8] = 1.0f;
    if (act) {
        int s = srcA[e];
        {
            const float4* ap = (const float4*)(attrA + e * 8);
            float4 v0 = ap[0], v1 = ap[1];
            ar[0] = v0.x; ar[1] = v0.y; ar[2] = v0.z; ar[3] = v0.w;
            ar[4] = v1.x; ar[5] = v1.y; ar[6] = v1.z; ar[7] = v1.w;
        }
        const float4* xp = (const float4*)(xsrc + s * 32);
        #pragma unroll
        for (int q = 0; q < 4; q++) {
            float4 v0 = xp[2 * q], v1 = xp[2 * q + 1];
            uint4 pk;
            pk.x = pack_trunc(v0.x, v0.y);
            pk.y = pack_trunc(v0.z, v0.w);
            pk.z = pack_trunc(v1.x, v1.y);
            pk.w = pack_trunc(v1.z, v1.w);
            xstage[wave][q * 64 + lane] = pk;
        }
        // linked-list insert (traversed in later kernels)
        int cd = is_io ? (NI + dstA[e]) : dstA[e];
        int old = atomicExch(&head[cd], p);
        nxt[p] = old;
    }

    f32x4 zero4 = {0.f, 0.f, 0.f, 0.f};
    #pragma unroll
    for (int mtile = 0; mtile < 4; mtile++) {
        // B-frag: x of edge (wave-local) mtile*16+(lane&15)
        uint4 braw = xstage[wave][quad * 64 + mtile * 16 + (lane & 15)];
        short8 bx = *(short8*)&braw;
        float mm0[4] = {0.f, 0.f, 0.f, 0.f};
        float mm1[4] = {0.f, 0.f, 0.f, 0.f};
        #pragma unroll
        for (int a = 0; a < 9; a++) {
            // D[m=o][n=edge]: col = edge -> attr is per-column constant
            f32x4 t0 = __builtin_amdgcn_mfma_f32_16x16x32_bf16(*(short8*)&wf[a][0], bx, zero4, 0, 0, 0);
            f32x4 t1 = __builtin_amdgcn_mfma_f32_16x16x32_bf16(*(short8*)&wf[a][1], bx, zero4, 0, 0, 0);
            float av = __shfl(ar[a], mtile * 16 + (lane & 15), 64);
            #pragma unroll
            for (int r = 0; r < 4; r++) {
                mm0[r] = fmaf(av, t0[r], mm0[r]);
                mm1[r] = fmaf(av, t1[r], mm1[r]);
            }
        }
        // dense bf16 store: rows o = quad*4+r (t0) and 16+quad*4+r (t1) of edge ecol
        int ecol = blockStart + wave * 64 + mtile * 16 + (lane & 15);
        if (ecol < relEnd) {
            unsigned d0 = f2bf(mm0[0]) | (f2bf(mm0[1]) << 16);
            unsigned d1 = f2bf(mm0[2]) | (f2bf(mm0[3]) << 16);
            unsigned d2 = f2bf(mm1[0]) | (f2bf(mm1[1]) << 16);
            unsigned d3 = f2bf(mm1[2]) | (f2bf(mm1[3]) << 16);
            unsigned short* mrow = msgb + (size_t)ecol * 32;
            *(uint2*)(mrow + quad * 4)      = make_uint2(d0, d1);
            *(uint2*)(mrow + 16 + quad * 4) = make_uint2(d2, d3);
        }
    }
}

// ---------------------------------------------------------------- unpack-add one bf16 msg row (64 B) into fp32 acc
__device__ __forceinline__ void add_msg_row(const unsigned short* mrow, float* ms) {
    const uint4* mr = (const uint4*)mrow;
    uint4 v0 = mr[0], v1 = mr[1], v2 = mr[2], v3 = mr[3];
    ms[0]  += bflo(v0.x); ms[1]  += bfhi(v0.x); ms[2]  += bflo(v0.y); ms[3]  += bfhi(v0.y);
    ms[4]  += bflo(v0.z); ms[5]  += bfhi(v0.z); ms[6]  += bflo(v0.w); ms[7]  += bfhi(v0.w);
    ms[8]  += bflo(v1.x); ms[9]  += bfhi(v1.x); ms[10] += bflo(v1.y); ms[11] += bfhi(v1.y);
    ms[12] += bflo(v1.z); ms[13] += bfhi(v1.z); ms[14] += bflo(v1.w); ms[15] += bfhi(v1.w);
    ms[16] += bflo(v2.x); ms[17] += bfhi(v2.x); ms[18] += bflo(v2.y); ms[19] += bfhi(v2.y);
    ms[20] += bflo(v2.z); ms[21] += bfhi(v2.z); ms[22] += bflo(v2.w); ms[23] += bfhi(v2.w);
    ms[24] += bflo(v3.x); ms[25] += bfhi(v3.x); ms[26] += bflo(v3.y); ms[27] += bfhi(v3.y);
    ms[28] += bflo(v3.z); ms[29] += bfhi(v3.z); ms[30] += bflo(v3.w); ms[31] += bfhi(v3.w);
}

// ---------------------------------------------------------------- org nodes: walk list, finish L1, prep L2
__global__ __launch_bounds__(256) void k_org(
    const float* __restrict__ x_org, const float* __restrict__ ws,
    const float* __restrict__ Wr_io, const float* __restrict__ b_io,
    const float* __restrict__ Wm2, const float* __restrict__ bm2,
    float* __restrict__ y2z2)
{
    int n = blockIdx.x * 256 + threadIdx.x;
    if (n >= NO) return;
    const int* head = (const int*)(ws + OFF_HEAD);
    const int* nxt  = (const int*)(ws + OFF_NXT);
    const unsigned short* msgb = (const unsigned short*)(ws + OFF_MSG);

    float ms[32];
    #pragma unroll
    for (int o = 0; o < 32; o++) ms[o] = 0.0f;
    for (int e = head[NI + n]; e != -1; e = nxt[e])
        add_msg_row(msgb + (size_t)e * 32, ms);

    float xr[32];
    const float4* xp = (const float4*)(x_org + n * 32);
    #pragma unroll
    for (int q = 0; q < 8; q++) {
        float4 v = xp[q];
        xr[q * 4 + 0] = v.x; xr[q * 4 + 1] = v.y; xr[q * 4 + 2] = v.z; xr[q * 4 + 3] = v.w;
    }
    float h[32];
    #pragma unroll 4
    for (int o = 0; o < 32; o++) {
        float s = b_io[o] + ms[o];
        #pragma unroll
        for (int i = 0; i < 32; i++) s = fmaf(xr[i], Wr_io[i * 32 + o], s);   // wave-uniform -> s_load
        h[o] = sigmoidf_fast(s);
    }
    float z2 = 0.0f;
    #pragma unroll
    for (int i = 0; i < 32; i++) z2 = fmaf(h[i], bm2[i], z2);
    float* yz = y2z2 + n * 12;
    yz[0] = z2;
    #pragma unroll
    for (int a = 0; a < 8; a++) {
        float s = 0.0f;
        #pragma unroll
        for (int i = 0; i < 32; i++) s = fmaf(h[i], Wm2[a * 32 + i], s);
        yz[1 + a] = s;
    }
}

// ---------------------------------------------------------------- indivi nodes: single walk (L1 sum + L2 msg), finish, out
__global__ __launch_bounds__(256) void k_out(
    const float* __restrict__ x_ind, const float* __restrict__ ws,
    const float* __restrict__ Wr_oi, const float* __restrict__ b_oi,
    const int* __restrict__ src_oi, const float* __restrict__ attr_oi,
    const float* __restrict__ Wr2, const float* __restrict__ b2,
    const float* __restrict__ y2z2,
    float* __restrict__ out)
{
    int d = blockIdx.x * 256 + threadIdx.x;
    if (d >= NI) return;
    const int* head = (const int*)(ws + OFF_HEAD);
    const int* nxt  = (const int*)(ws + OFF_NXT);
    const unsigned short* msgb = (const unsigned short*)(ws + OFF_MSG);

    float ms[32];
    #pragma unroll
    for (int o = 0; o < 32; o++) ms[o] = 0.0f;
    float m2acc = 0.0f;
    for (int e = head[d]; e != -1; e = nxt[e]) {
        add_msg_row(msgb + (size_t)e * 32, ms);
        // layer-2 message for this edge (e < NE, oi relation)
        int s = src_oi[e];
        const float* yz = y2z2 + s * 12;
        const float4* ap = (const float4*)(attr_oi + e * 8);
        float4 a0 = ap[0], a1 = ap[1];
        float m = yz[0];
        m = fmaf(a0.x, yz[1], m); m = fmaf(a0.y, yz[2], m);
        m = fmaf(a0.z, yz[3], m); m = fmaf(a0.w, yz[4], m);
        m = fmaf(a1.x, yz[5], m); m = fmaf(a1.y, yz[6], m);
        m = fmaf(a1.z, yz[7], m); m = fmaf(a1.w, yz[8], m);
        m2acc += m;
    }
    float xr[32];
    const float4* xp = (const float4*)(x_ind + d * 32);
    #pragma unroll
    for (int q = 0; q < 8; q++) {
        float4 v = xp[q];
        xr[q * 4 + 0] = v.x; xr[q * 4 + 1] = v.y; xr[q * 4 + 2] = v.z; xr[q * 4 + 3] = v.w;
    }
    float t = b2[0] + m2acc;
    #pragma unroll 4
    for (int o = 0; o < 32; o++) {
        float s = b_oi[o] + ms[o];
        #pragma unroll
        for (int i = 0; i < 32; i++) s = fmaf(xr[i], Wr_oi[i * 32 + o], s);   // wave-uniform -> s_load
        t = fmaf(sigmoidf_fast(s), Wr2[o], t);
    }
    out[d] = sigmoidf_fast(t);
}

// ---------------------------------------------------------------- launch
extern "C" void kernel_launch(void* const* d_in, const int* in_sizes, int n_in,
                              void* d_out, int out_size, void* d_ws, size_t ws_size,
                              hipStream_t stream)
{
    const float* x_ind   = (const float*)d_in[0];
    const float* x_org   = (const float*)d_in[1];
    const int*   src_oi  = (const int*)d_in[2];
    const int*   dst_oi  = (const int*)d_in[3];
    const float* attr_oi = (const float*)d_in[4];
    const int*   src_io  = (const int*)d_in[5];
    const int*   dst_io  = (const int*)d_in[6];
    const float* attr_io = (const float*)d_in[7];
    const float* Wm_oi   = (const float*)d_in[8];
    const float* bm_oi   = (const float*)d_in[9];
    const float* Wr_oi   = (const float*)d_in[10];
    const float* b_oi    = (const float*)d_in[11];
    const float* Wm_io   = (const float*)d_in[12];
    const float* bm_io   = (const float*)d_in[13];
    const float* Wr_io   = (const float*)d_in[14];
    const float* b_io    = (const float*)d_in[15];
    const float* Wm2     = (const float*)d_in[16];
    const float* bm2     = (const float*)d_in[17];
    const float* Wr2     = (const float*)d_in[18];
    const float* b2      = (const float*)d_in[19];

    float* ws   = (float*)d_ws;
    float* y2z2 = ws + OFF_Y2Z2;
    float* out  = (float*)d_out;

    k_init<<<B_INIT, 256, 0, stream>>>(Wm_oi, bm_oi, Wm_io, bm_io, ws);

    k_msg<<<2 * B_EDGE, 256, 0, stream>>>(
        src_oi, dst_oi, attr_oi, src_io, dst_io, attr_io, x_ind, x_org, ws);

    k_org<<<B_ORG, 256, 0, stream>>>(
        x_org, ws, Wr_io, b_io, Wm2, bm2, y2z2);

    k_out<<<B_IND, 256, 0, stream>>>(
        x_ind, ws, Wr_oi, b_oi, src_oi, attr_oi, Wr2, b2, y2z2, out);
}